// Round 3
// baseline (1571.287 us; speedup 1.0000x reference)
//
#include <hip/hip_runtime.h>

#ifndef __has_builtin
#define __has_builtin(x) 0
#endif

typedef float v2 __attribute__((ext_vector_type(2)));

// ---- fast HW transcendentals (v_exp_f32 computes 2^x; v_rcp_f32) ----
__device__ __forceinline__ float fast_exp2(float x) {
#if __has_builtin(__builtin_amdgcn_exp2f)
  return __builtin_amdgcn_exp2f(x);
#else
  return exp2f(x);
#endif
}
__device__ __forceinline__ float fast_rcp(float x) {
#if __has_builtin(__builtin_amdgcn_rcpf)
  return __builtin_amdgcn_rcpf(x);
#else
  return 1.0f / x;
#endif
}

namespace {
constexpr int kB = 131072;
constexpr int kSeq = 150;
constexpr int kD = 2;
constexpr int kH = 64;
constexpr int kPred = 150;
constexpr int kSteps = kPred - 1;            // 149
constexpr float kDt = 150.0f / 149.0f;       // linspace(0,150,150) spacing
constexpr float kC = 2.8853900817779268f;    // 2*log2(e)
constexpr float kClamp = 30.0f;              // exp2 arg clamp (sigma err <1e-9)
constexpr int kSplit = 4;                    // lanes per batch element
constexpr int kHper = kH / kSplit;           // 16 hidden units per lane
constexpr int kPairs = kHper / 2;            // 8 weight pairs per array
constexpr int kBlock = 256;
constexpr int kElemsPerBlock = kBlock / kSplit;  // 64
}  // namespace

// Butterfly add within each 4-lane quad via DPP quad_perm (fuses to
// v_add_f32_dpp). xor1: perm(1,0,3,2)=0xB1 ; xor2: perm(2,3,0,1)=0x4E
template <int PAT>
__device__ __forceinline__ float dpp_add(float v) {
  int s = __builtin_amdgcn_update_dpp(0, __float_as_int(v), PAT, 0xF, 0xF, true);
  return v + __int_as_float(s);
}

// f(y) = tanh(y@W1+b1)@W2 + b2, folded:
//   tanh(q) = 1 - 2*rcp(1 + exp2(q*2log2e))
//   per-lane (16 of 64 hidden units) in 4 groups of 4 with a SHARED
//   reciprocal: r_i = (prod_{j!=i} s_j) * rcp(prod s_j), s = 1+exp2(p).
// Pre-activation and accumulation use hand-emitted VOP3P packed-f32 math
// (v_pk_fma_f32 with op_sel broadcast of the state pair). The asm also
// pins the *scaled* weight pairs in VGPRs: the compiler can no longer
// refold kC into the state and remat the raw W1/W2 loads in-loop (the
// VGPR_Count=60..64 pathology of rounds 1-2).
__global__ __launch_bounds__(kBlock, 3) void ode_kernel(
    const float* __restrict__ x, const float* __restrict__ W1,
    const float* __restrict__ b1, const float* __restrict__ W2,
    const float* __restrict__ b2, float* __restrict__ out) {
  const int t = threadIdx.x;
  const int part = t & (kSplit - 1);
  const int j0 = part * kHper;

  // ---- weight pairs, register-resident ----
  v2 wx[kPairs], wy[kPairs], wb[kPairs], wz[kPairs], ww[kPairs];
  {
    const v2* w1r0 = reinterpret_cast<const v2*>(W1 + j0);        // 8B aligned
    const v2* w1r1 = reinterpret_cast<const v2*>(W1 + kH + j0);
    const v2* b1p = reinterpret_cast<const v2*>(b1 + j0);
#pragma unroll
    for (int i = 0; i < kPairs; ++i) {
      wx[i] = w1r0[i] * kC;
      wy[i] = w1r1[i] * kC;
      wb[i] = b1p[i] * kC;
      const int j = j0 + 2 * i;
      wz[i].x = -2.0f * W2[2 * j];
      wz[i].y = -2.0f * W2[2 * (j + 1)];
      ww[i].x = -2.0f * W2[2 * j + 1];
      ww[i].y = -2.0f * W2[2 * (j + 1) + 1];
    }
  }
  // lane partial base: 0.25*b2[d] + sum_own_j W2[j][d]  (wz = -2*W2)
  float pb0 = 0.25f * b2[0];
  float pb1 = 0.25f * b2[1];
#pragma unroll
  for (int i = 0; i < kPairs; ++i) {
    pb0 = fmaf(-0.5f, wz[i].x + wz[i].y, pb0);
    pb1 = fmaf(-0.5f, ww[i].x + ww[i].y, pb1);
  }
  // Opacity barrier: values become asm-defined -> non-rematerializable.
#pragma unroll
  for (int i = 0; i < kPairs; ++i) {
    asm volatile("" : "+v"(wx[i]), "+v"(wy[i]), "+v"(wb[i]), "+v"(wz[i]),
                      "+v"(ww[i]));
  }

  const long elem = (long)blockIdx.x * kElemsPerBlock + (t >> 2);
  const float* xp = x + elem * (long)(kSeq * kD) + (kSeq - 1) * kD;
  v2 y = *reinterpret_cast<const v2*>(xp);  // 8B aligned (offset 298*4)
  float* op = out + elem * (long)(kPred * kD);

  auto feval = [&](v2 u) -> v2 {
    v2 accA0, accA1, accB0, accB1;
// One group of 4 hidden units (pairs iA, iB). Pre-activation:
//   p = u0*wx + u1*wy + wb  via two v_pk_fma_f32; op_sel broadcasts u.hi
//   (inst 1) / u.lo (inst 2) so the state never needs duplicating.
#define GRP(iA, iB, FIRST)                                                    \
  {                                                                           \
    v2 pA, pB;                                                                \
    asm("v_pk_fma_f32 %0, %1, %2, %3 op_sel:[1,0,0] op_sel_hi:[1,1,1]"        \
        : "=v"(pA) : "v"(u), "v"(wy[iA]), "v"(wb[iA]));                       \
    asm("v_pk_fma_f32 %0, %1, %2, %0 op_sel:[0,0,0] op_sel_hi:[0,1,1]"        \
        : "+v"(pA) : "v"(u), "v"(wx[iA]));                                    \
    asm("v_pk_fma_f32 %0, %1, %2, %3 op_sel:[1,0,0] op_sel_hi:[1,1,1]"        \
        : "=v"(pB) : "v"(u), "v"(wy[iB]), "v"(wb[iB]));                       \
    asm("v_pk_fma_f32 %0, %1, %2, %0 op_sel:[0,0,0] op_sel_hi:[0,1,1]"        \
        : "+v"(pB) : "v"(u), "v"(wx[iB]));                                    \
    float s0 = 1.0f + fast_exp2(fminf(pA.x, kClamp));                         \
    float s1 = 1.0f + fast_exp2(fminf(pA.y, kClamp));                         \
    float s2 = 1.0f + fast_exp2(fminf(pB.x, kClamp));                         \
    float s3 = 1.0f + fast_exp2(fminf(pB.y, kClamp));                         \
    float m01 = s0 * s1, m23 = s2 * s3;                                       \
    float R = fast_rcp(m01 * m23);                                            \
    float t01 = m23 * R, t23 = m01 * R;                                       \
    v2 rA, rB;                                                                \
    rA.x = s1 * t01;                                                          \
    rA.y = s0 * t01;                                                          \
    rB.x = s3 * t23;                                                          \
    rB.y = s2 * t23;                                                          \
    if (FIRST) {                                                              \
      asm("v_pk_mul_f32 %0, %1, %2" : "=v"(accA0) : "v"(rA), "v"(wz[iA]));    \
      asm("v_pk_mul_f32 %0, %1, %2" : "=v"(accA1) : "v"(rA), "v"(ww[iA]));    \
      asm("v_pk_mul_f32 %0, %1, %2" : "=v"(accB0) : "v"(rB), "v"(wz[iB]));    \
      asm("v_pk_mul_f32 %0, %1, %2" : "=v"(accB1) : "v"(rB), "v"(ww[iB]));    \
    } else {                                                                  \
      asm("v_pk_fma_f32 %0, %1, %2, %0" : "+v"(accA0) : "v"(rA), "v"(wz[iA]));\
      asm("v_pk_fma_f32 %0, %1, %2, %0" : "+v"(accA1) : "v"(rA), "v"(ww[iA]));\
      asm("v_pk_fma_f32 %0, %1, %2, %0" : "+v"(accB0) : "v"(rB), "v"(wz[iB]));\
      asm("v_pk_fma_f32 %0, %1, %2, %0" : "+v"(accB1) : "v"(rB), "v"(ww[iB]));\
    }                                                                         \
  }
    GRP(0, 1, true)
    GRP(2, 3, false)
    GRP(4, 5, false)
    GRP(6, 7, false)
#undef GRP
    v2 a0 = accA0 + accB0;
    v2 a1 = accA1 + accB1;
    v2 f;
    f.x = pb0 + a0.x + a0.y;
    f.y = pb1 + a1.x + a1.y;
    // 4-lane butterfly: every lane ends with the full 64-hidden sum
    // (bitwise identical across the quad: fp add is commutative).
    f.x = dpp_add<0x4E>(dpp_add<0xB1>(f.x));
    f.y = dpp_add<0x4E>(dpp_add<0xB1>(f.y));
    return f;
  };

  // previous even-index state (for paired float4 stores)
  v2 py = y;
  constexpr float DT = kDt, DT3 = kDt / 3.0f, DT8 = kDt / 8.0f;

  for (int s = 1; s <= kSteps; ++s) {
    v2 k1 = feval(y);
    v2 k2 = feval(__builtin_elementwise_fma((v2)DT3, k1, y));
    v2 k3 = feval(__builtin_elementwise_fma(
        (v2)DT, k2, __builtin_elementwise_fma((v2)(-DT3), k1, y)));
    v2 k4 = feval(__builtin_elementwise_fma((v2)DT, (k1 - k2) + k3, y));
    y = __builtin_elementwise_fma(
        (v2)DT8, __builtin_elementwise_fma((v2)3.0f, k2 + k3, k1) + k4, y);

    if (s & 1) {
      if (part == 0) {
        // write times (s-1, s) as one 16B store; offsets are 16B-aligned
        float4 v = make_float4(py.x, py.y, y.x, y.y);
        *reinterpret_cast<float4*>(op + (long)(s - 1) * 2) = v;
      }
    } else {
      py = y;
    }
  }
}

extern "C" void kernel_launch(void* const* d_in, const int* in_sizes, int n_in,
                              void* d_out, int out_size, void* d_ws,
                              size_t ws_size, hipStream_t stream) {
  const float* x = (const float*)d_in[0];
  const float* W1 = (const float*)d_in[1];
  const float* b1 = (const float*)d_in[2];
  const float* W2 = (const float*)d_in[3];
  const float* b2 = (const float*)d_in[4];
  float* out = (float*)d_out;

  dim3 grid(kB * kSplit / kBlock);  // 2048 elems/block -> 8192 blocks
  dim3 block(kBlock);
  hipLaunchKernelGGL(ode_kernel, grid, block, 0, stream, x, W1, b1, W2, b2,
                     out);
}